// Round 2
// baseline (9819.349 us; speedup 1.0000x reference)
//
#include <hip/hip_runtime.h>

// Problem constants (B, H, W) from the reference.
#define BB 8
#define HH 1080
#define WW 1920
constexpr int HWc  = HH * WW;         // 2,073,600
constexpr int Ntot = BB * HWc;        // 16,588,800

// ===========================================================================
// Interleaved-accumulator path (primary).
// acc[(b*HW + p)*S + {0,1,2}] accumulates {vx, vy, w}.  S = 4 (16B, line-
// aligned) or 3 (12B, denser but 12.5% line-straddling corners).
// All 3 atomics of a corner now hit ONE cache line instead of three planes.
// ===========================================================================
template <int S>
__global__ __launch_bounds__(256) void splat_i(const float* __restrict__ flow,
                                               const float* __restrict__ depth,
                                               float* __restrict__ acc) {
    int idx = blockIdx.x * 256 + threadIdx.x;
    if (idx >= Ntot) return;
    int b = idx / HWc;
    int p = idx - b * HWc;
    int y = p / WW;
    int x = p - y * WW;

    const size_t fbase = (size_t)b * 2 * HWc;
    float fx = flow[fbase + p];
    float fy = flow[fbase + HWc + p];
    float x2 = (float)x + fx;
    float y2 = (float)y + fy;
    if (!(x2 >= 0.f && x2 <= (float)(WW - 1) && y2 >= 0.f && y2 <= (float)(HH - 1)))
        return;  // invalid projection contributes nothing

    float w = depth[(size_t)b * HWc + p];
    int ixL = min(max((int)floorf(x2), 0), WW - 1);
    int iyT = min(max((int)floorf(y2), 0), HH - 1);
    int ixR = min(ixL + 1, WW - 1);   // border: coincides with ixL -> double add
    int iyB = min(iyT + 1, HH - 1);

    float vx = -fx * w;
    float vy = -fy * w;

    float* base = acc + (size_t)b * HWc * S;
    int c0 = iyT * WW + ixL;
    int c1 = iyT * WW + ixR;
    int c2 = iyB * WW + ixL;
    int c3 = iyB * WW + ixR;
    int cs[4] = {c0, c1, c2, c3};
#pragma unroll
    for (int k = 0; k < 4; ++k) {
        float* t = base + (size_t)cs[k] * S;
        atomicAdd(t + 0, vx);
        atomicAdd(t + 1, vy);
        atomicAdd(t + 2, w);
    }
}

// Average: out(planar, B,2,H,W) = acc.{x,y}/acc.z where z>0, else 0.
// Writes EVERY output pixel -> no d_out memset needed.
template <int S>
__global__ __launch_bounds__(256) void avg_i(const float* __restrict__ acc,
                                             float* __restrict__ out) {
    int idx = blockIdx.x * 256 + threadIdx.x;
    if (idx >= Ntot) return;
    int b = idx / HWc;
    int p = idx - b * HWc;

    float vx, vy, c;
    if constexpr (S == 4) {
        const float4 a = ((const float4*)acc)[idx];   // one 16B coalesced load
        vx = a.x; vy = a.y; c = a.z;
    } else {
        const float* a = acc + (size_t)idx * S;
        vx = a[0]; vy = a[1]; c = a[2];
    }
    size_t fbase = (size_t)b * 2 * HWc;
    float inv = (c > 0.f) ? (1.f / c) : 0.f;          // holes -> 0
    out[fbase + p]       = vx * inv;
    out[fbase + HWc + p] = vy * inv;
}

// ===========================================================================
// Hole fill, generic over where the count lives:
//   count(q) = cw[(size_t)q * S + OFF]   (S=4/3: acc.z ; S=1,OFF=0: plane)
// Reads only filled pixels, writes only holes -> in-place safe.
// ===========================================================================
template <int S, int OFF>
__global__ __launch_bounds__(256) void fill_g(float* __restrict__ out,
                                              const float* __restrict__ cw) {
    int idx = blockIdx.x * 256 + threadIdx.x;
    if (idx >= Ntot) return;
    if (cw[(size_t)idx * S + OFF] > 0.f) return;      // filled: keep value

    int b = idx / HWc;
    int p = idx - b * HWc;
    int y = p / WW;
    int x = p - y * WW;

    const float* cb = cw + (size_t)b * HWc * S + OFF;
    const float* o0 = out + (size_t)b * 2 * HWc;
    const float* o1 = o0 + HWc;

    float s = 0.f, s0 = 0.f, s1 = 0.f;
    // left
    for (int j = x - 1; j >= 0; --j) {
        int q = y * WW + j;
        if (cb[(size_t)q * S] > 0.f) { s += 1.f; s0 += o0[q]; s1 += o1[q]; break; }
    }
    // right
    for (int j = x + 1; j < WW; ++j) {
        int q = y * WW + j;
        if (cb[(size_t)q * S] > 0.f) { s += 1.f; s0 += o0[q]; s1 += o1[q]; break; }
    }
    // up
    for (int i = y - 1; i >= 0; --i) {
        int q = i * WW + x;
        if (cb[(size_t)q * S] > 0.f) { s += 1.f; s0 += o0[q]; s1 += o1[q]; break; }
    }
    // down
    for (int i = y + 1; i < HH; ++i) {
        int q = i * WW + x;
        if (cb[(size_t)q * S] > 0.f) { s += 1.f; s0 += o0[q]; s1 += o1[q]; break; }
    }

    if (s > 0.f) {
        ((float*)o0)[p] = s0 / s;
        ((float*)o1)[p] = s1 / s;
    }
    // else keep 0 (avg wrote 0 for holes)
}

// ===========================================================================
// Planar fallback (round-1 structure), used only if ws_size is too small for
// the interleaved accumulator.
// ===========================================================================
__global__ __launch_bounds__(256) void splat_p(const float* __restrict__ flow,
                                               const float* __restrict__ depth,
                                               float* __restrict__ out,
                                               float* __restrict__ cnt) {
    int idx = blockIdx.x * 256 + threadIdx.x;
    if (idx >= Ntot) return;
    int b = idx / HWc;
    int p = idx - b * HWc;
    int y = p / WW;
    int x = p - y * WW;
    const size_t fbase = (size_t)b * 2 * HWc;
    float fx = flow[fbase + p];
    float fy = flow[fbase + HWc + p];
    float x2 = (float)x + fx, y2 = (float)y + fy;
    if (!(x2 >= 0.f && x2 <= (float)(WW - 1) && y2 >= 0.f && y2 <= (float)(HH - 1)))
        return;
    float w = depth[(size_t)b * HWc + p];
    int ixL = min(max((int)floorf(x2), 0), WW - 1);
    int iyT = min(max((int)floorf(y2), 0), HH - 1);
    int ixR = min(ixL + 1, WW - 1);
    int iyB = min(iyT + 1, HH - 1);
    float vx = -fx * w, vy = -fy * w;
    float* o0 = out + fbase;
    float* o1 = o0 + HWc;
    float* cc = cnt + (size_t)b * HWc;
    int cs[4] = {iyT * WW + ixL, iyT * WW + ixR, iyB * WW + ixL, iyB * WW + ixR};
#pragma unroll
    for (int k = 0; k < 4; ++k) {
        atomicAdd(o0 + cs[k], vx);
        atomicAdd(o1 + cs[k], vy);
        atomicAdd(cc + cs[k], w);
    }
}

__global__ __launch_bounds__(256) void avg_p(float* __restrict__ out,
                                             const float* __restrict__ cnt) {
    int idx = blockIdx.x * 256 + threadIdx.x;
    if (idx >= Ntot) return;
    float c = cnt[idx];
    if (c > 0.f) {
        int b = idx / HWc;
        int p = idx - b * HWc;
        size_t fbase = (size_t)b * 2 * HWc;
        out[fbase + p]       /= c;
        out[fbase + HWc + p] /= c;
    }
}

extern "C" void kernel_launch(void* const* d_in, const int* in_sizes, int n_in,
                              void* d_out, int out_size, void* d_ws, size_t ws_size,
                              hipStream_t stream) {
    const float* flow  = (const float*)d_in[0];   // (B,2,H,W)
    const float* depth = (const float*)d_in[1];   // (B,1,H,W)
    float* out = (float*)d_out;                   // (B,2,H,W)

    const int threads = 256;
    const int grid = (Ntot + threads - 1) / threads;

    const size_t need4 = (size_t)Ntot * 4 * sizeof(float);  // 265 MB
    const size_t need3 = (size_t)Ntot * 3 * sizeof(float);  // 199 MB

    if (ws_size >= need4) {
        float* acc = (float*)d_ws;
        hipMemsetAsync(acc, 0, need4, stream);
        splat_i<4><<<grid, threads, 0, stream>>>(flow, depth, acc);
        avg_i<4><<<grid, threads, 0, stream>>>(acc, out);
        fill_g<4, 2><<<grid, threads, 0, stream>>>(out, acc);
    } else if (ws_size >= need3) {
        float* acc = (float*)d_ws;
        hipMemsetAsync(acc, 0, need3, stream);
        splat_i<3><<<grid, threads, 0, stream>>>(flow, depth, acc);
        avg_i<3><<<grid, threads, 0, stream>>>(acc, out);
        fill_g<3, 2><<<grid, threads, 0, stream>>>(out, acc);
    } else {
        // Planar fallback (round-1 layout): cnt in ws, sums in d_out.
        float* cnt = (float*)d_ws;                 // 66 MB
        hipMemsetAsync(out, 0, (size_t)Ntot * 2 * sizeof(float), stream);
        hipMemsetAsync(cnt, 0, (size_t)Ntot * sizeof(float), stream);
        splat_p<<<grid, threads, 0, stream>>>(flow, depth, out, cnt);
        avg_p<<<grid, threads, 0, stream>>>(out, cnt);
        fill_g<1, 0><<<grid, threads, 0, stream>>>(out, cnt);
    }
}

// Round 3
// 2312.211 us; speedup vs baseline: 4.2467x; 4.2467x over previous
//
#include <hip/hip_runtime.h>

// Problem constants (B, H, W) from the reference.
#define BB 8
#define HH 1080
#define WW 1920
constexpr int HWc  = HH * WW;          // 2,073,600
constexpr int Ntot = BB * HWc;         // 16,588,800

constexpr int TILE = 64;               // source tile side
constexpr int MAR  = 32;               // margin: P(|N(0,10)| > 32) ~ 1.4e-3 per tail
constexpr int REG  = TILE + 2 * MAR;   // 128 -> LDS plane 128*128*4B = 64 KB exactly
constexpr int WT   = (WW + TILE - 1) / TILE;  // 30 tiles in x
constexpr int HT   = (HH + TILE - 1) / TILE;  // 17 tiles in y (last partial)

// Global accumulator in d_ws: 3 planar channels {sum(-fx*w), sum(-fy*w), sum(w)},
// each Ntot floats (total 199 MB; R2 proved ws_size >= 199 MB since splat_i ran).

// ---------------------------------------------------------------------------
// Pre-pass: handle the RARE corners that fall outside their source tile's
// expanded region, with global atomics. Runs BEFORE the tile kernels, so
// atomic adds never race with the tile kernels' non-atomic RMW writeback.
// Predicate must match tile_k's in-region test exactly (integer arithmetic).
// ---------------------------------------------------------------------------
__global__ __launch_bounds__(256) void prepass_k(const float* __restrict__ flow,
                                                 const float* __restrict__ depth,
                                                 float* __restrict__ acc) {
    int idx = blockIdx.x * 256 + threadIdx.x;
    if (idx >= Ntot) return;
    int b = idx / HWc;
    int p = idx - b * HWc;
    int y = p / WW;
    int x = p - y * WW;

    const size_t fbase = (size_t)b * 2 * HWc;
    float fx = flow[fbase + p];
    float fy = flow[fbase + HWc + p];
    float x2 = (float)x + fx;
    float y2 = (float)y + fy;
    if (!(x2 >= 0.f && x2 <= (float)(WW - 1) && y2 >= 0.f && y2 <= (float)(HH - 1)))
        return;

    int ixL = min(max((int)floorf(x2), 0), WW - 1);
    int iyT = min(max((int)floorf(y2), 0), HH - 1);
    int ixR = min(ixL + 1, WW - 1);
    int iyB = min(iyT + 1, HH - 1);

    // Expanded region of this source's tile.
    int rx0 = (x / TILE) * TILE - MAR;
    int ry0 = (y / TILE) * TILE - MAR;

    int cxs[2] = {ixL, ixR};
    int cys[2] = {iyT, iyB};
    bool anyOut = false;
#pragma unroll
    for (int a = 0; a < 2; ++a)
#pragma unroll
        for (int c = 0; c < 2; ++c) {
            int cx = cxs[c], cy = cys[a];
            if (!(cx >= rx0 && cx < rx0 + REG && cy >= ry0 && cy < ry0 + REG))
                anyOut = true;
        }
    if (!anyOut) return;   // ~99.96% of threads exit here (wave-uniform mostly)

    float w = depth[(size_t)b * HWc + p];
    float vx = -fx * w;
    float vy = -fy * w;
    float* a0 = acc + (size_t)b * HWc;
    float* a1 = acc + (size_t)Ntot + (size_t)b * HWc;
    float* a2 = acc + (size_t)2 * Ntot + (size_t)b * HWc;
#pragma unroll
    for (int a = 0; a < 2; ++a)
#pragma unroll
        for (int c = 0; c < 2; ++c) {
            int cx = cxs[c], cy = cys[a];
            if (!(cx >= rx0 && cx < rx0 + REG && cy >= ry0 && cy < ry0 + REG)) {
                int q = cy * WW + cx;
                atomicAdd(a0 + q, vx);
                atomicAdd(a1 + q, vy);
                atomicAdd(a2 + q, w);
            }
        }
}

// ---------------------------------------------------------------------------
// Tile kernel: one block per 64x64 source tile (of one image). For each of the
// 3 channels: zero a 128x128 LDS plane, splat the tile's sources into it with
// LDS atomics, then non-atomic read-add-write into the global planar channel.
// Launched in 4 checkerboard phases (px,py in {0,1}): same-phase regions are
// [x0-32, x0+96) with stride 128 -> exactly adjacent, never overlapping.
// ---------------------------------------------------------------------------
__global__ __launch_bounds__(256) void tile_k(const float* __restrict__ flow,
                                              const float* __restrict__ depth,
                                              float* __restrict__ acc,
                                              int px, int py) {
    __shared__ float sm[REG * REG];    // 64 KB
    const int tx = px + 2 * blockIdx.x;
    const int ty = py + 2 * blockIdx.y;
    const int b  = blockIdx.z;
    const int x0 = tx * TILE, y0 = ty * TILE;
    const int rx0 = x0 - MAR, ry0 = y0 - MAR;
    const int tid = threadIdx.x;

    const size_t fbase = (size_t)b * 2 * HWc;
    const float* fxp = flow + fbase;
    const float* fyp = fxp + HWc;
    const float* dp  = depth + (size_t)b * HWc;

    for (int ch = 0; ch < 3; ++ch) {
        // zero LDS (float4 stores, 16 iters)
        float4* sm4 = (float4*)sm;
        for (int i = tid; i < REG * REG / 4; i += 256)
            sm4[i] = make_float4(0.f, 0.f, 0.f, 0.f);
        __syncthreads();

        // accumulate this tile's sources (16 per thread)
        for (int k = 0; k < TILE * TILE / 256; ++k) {
            int s  = k * 256 + tid;
            int sy = s >> 6, sx = s & 63;
            int gy = y0 + sy, gx = x0 + sx;
            if (gy < HH) {
                int p = gy * WW + gx;
                float fx = fxp[p], fy = fyp[p];
                float x2 = (float)gx + fx, y2 = (float)gy + fy;
                if (x2 >= 0.f && x2 <= (float)(WW - 1) &&
                    y2 >= 0.f && y2 <= (float)(HH - 1)) {
                    float w = dp[p];
                    int ixL = min(max((int)floorf(x2), 0), WW - 1);
                    int iyT = min(max((int)floorf(y2), 0), HH - 1);
                    int ixR = min(ixL + 1, WW - 1);
                    int iyB = min(iyT + 1, HH - 1);
                    float val = (ch == 0) ? -fx * w : (ch == 1) ? -fy * w : w;
                    int cxs[2] = {ixL, ixR};
                    int cys[2] = {iyT, iyB};
#pragma unroll
                    for (int a = 0; a < 2; ++a)
#pragma unroll
                        for (int c = 0; c < 2; ++c) {
                            int cx = cxs[c], cy = cys[a];
                            if (cx >= rx0 && cx < rx0 + REG &&
                                cy >= ry0 && cy < ry0 + REG)
                                atomicAdd(&sm[(cy - ry0) * REG + (cx - rx0)], val);
                            // else: handled by prepass_k
                        }
                }
            }
        }
        __syncthreads();

        // non-atomic RMW writeback (skip zeros: margins are mostly empty)
        float* plane = acc + (size_t)ch * Ntot + (size_t)b * HWc;
        for (int i = tid; i < REG * REG; i += 256) {
            int ry = i >> 7, cx = i & (REG - 1);
            int gy = ry0 + ry, gx = rx0 + cx;
            if ((unsigned)gy < (unsigned)HH && (unsigned)gx < (unsigned)WW) {
                float v = sm[i];
                if (v != 0.f) {
                    int q = gy * WW + gx;
                    plane[q] += v;
                }
            }
        }
        __syncthreads();
    }
}

// ---------------------------------------------------------------------------
// Average: out = acc.{vx,vy} / acc.w where w>0, else 0. Writes every pixel.
// ---------------------------------------------------------------------------
__global__ __launch_bounds__(256) void avg_k(const float* __restrict__ acc,
                                             float* __restrict__ out) {
    int idx = blockIdx.x * 256 + threadIdx.x;
    if (idx >= Ntot) return;
    int b = idx / HWc;
    int p = idx - b * HWc;
    float vx = acc[idx];
    float vy = acc[(size_t)Ntot + idx];
    float c  = acc[(size_t)2 * Ntot + idx];
    float inv = (c > 0.f) ? (1.f / c) : 0.f;
    size_t fbase = (size_t)b * 2 * HWc;
    out[fbase + p]       = vx * inv;
    out[fbase + HWc + p] = vy * inv;
}

// ---------------------------------------------------------------------------
// Hole fill: for count==0 pixels, average nearest filled pixel in each of the
// 4 axis directions. Reads only filled pixels, writes only holes.
// ---------------------------------------------------------------------------
__global__ __launch_bounds__(256) void fill_k(float* __restrict__ out,
                                              const float* __restrict__ cw) {
    int idx = blockIdx.x * 256 + threadIdx.x;
    if (idx >= Ntot) return;
    if (cw[idx] > 0.f) return;

    int b = idx / HWc;
    int p = idx - b * HWc;
    int y = p / WW;
    int x = p - y * WW;

    const float* cb = cw + (size_t)b * HWc;
    const float* o0 = out + (size_t)b * 2 * HWc;
    const float* o1 = o0 + HWc;

    float s = 0.f, s0 = 0.f, s1 = 0.f;
    for (int j = x - 1; j >= 0; --j) {
        int q = y * WW + j;
        if (cb[q] > 0.f) { s += 1.f; s0 += o0[q]; s1 += o1[q]; break; }
    }
    for (int j = x + 1; j < WW; ++j) {
        int q = y * WW + j;
        if (cb[q] > 0.f) { s += 1.f; s0 += o0[q]; s1 += o1[q]; break; }
    }
    for (int i = y - 1; i >= 0; --i) {
        int q = i * WW + x;
        if (cb[q] > 0.f) { s += 1.f; s0 += o0[q]; s1 += o1[q]; break; }
    }
    for (int i = y + 1; i < HH; ++i) {
        int q = i * WW + x;
        if (cb[q] > 0.f) { s += 1.f; s0 += o0[q]; s1 += o1[q]; break; }
    }

    if (s > 0.f) {
        ((float*)o0)[p] = s0 / s;
        ((float*)o1)[p] = s1 / s;
    }
}

extern "C" void kernel_launch(void* const* d_in, const int* in_sizes, int n_in,
                              void* d_out, int out_size, void* d_ws, size_t ws_size,
                              hipStream_t stream) {
    const float* flow  = (const float*)d_in[0];   // (B,2,H,W)
    const float* depth = (const float*)d_in[1];   // (B,1,H,W)
    float* out = (float*)d_out;                   // (B,2,H,W)
    float* acc = (float*)d_ws;                    // 3 planes x Ntot floats = 199 MB

    const int threads = 256;
    const int grid1d = (Ntot + threads - 1) / threads;

    // zero the accumulator (graph-capture-safe)
    hipMemsetAsync(acc, 0, (size_t)3 * Ntot * sizeof(float), stream);

    // rare out-of-region corners via global atomics (must precede tile phases)
    prepass_k<<<grid1d, threads, 0, stream>>>(flow, depth, acc);

    // 4 checkerboard phases of LDS-accumulated tiles
    for (int py = 0; py < 2; ++py) {
        for (int px = 0; px < 2; ++px) {
            int nx = (WT - px + 1) / 2;   // 15, 15
            int ny = (HT - py + 1) / 2;   // 9, 8
            dim3 g(nx, ny, BB);
            tile_k<<<g, threads, 0, stream>>>(flow, depth, acc, px, py);
        }
    }

    avg_k<<<grid1d, threads, 0, stream>>>(acc, out);
    fill_k<<<grid1d, threads, 0, stream>>>(out, acc + (size_t)2 * Ntot);
}